// Round 5
// baseline (265.136 us; speedup 1.0000x reference)
//
#include <hip/hip_runtime.h>

static constexpr int BLOCK = 256;
static constexpr int GRID  = 1536;            // ~6 persistent blocks/CU
static constexpr int SPT   = 4;               // samples per thread
static constexpr int TILE  = BLOCK * SPT;     // 1024 samples per block-tile
static constexpr int TF4   = TILE * 3 / 4;    // 768 float4 of logits/soft per tile
static constexpr float LOG2E = 1.4426950408889634f;
static constexpr float LN2   = 0.6931471805599453f;

// (kl + ce) in log2 domain; 0.5*ln2 folded into final scale.
__device__ __forceinline__ float sample2(float l0, float l1, float l2,
                                         float t0, float t1, float t2,
                                         float c, int lab) {
    float low  = fminf(2.5f + (0.6f - c) * 2.0f, 3.0f);
    float invT = (c > 0.9f) ? (2.0f / 3.0f)
               : (c > 0.6f) ? 0.5f
               : __builtin_amdgcn_rcpf(low);

    float sc = invT * LOG2E;
    float b0 = l0 * sc, b1 = l1 * sc, b2 = l2 * sc;
    float m  = fmaxf(b0, fmaxf(b1, b2));
    float S  = __builtin_amdgcn_exp2f(b0 - m) + __builtin_amdgcn_exp2f(b1 - m)
             + __builtin_amdgcn_exp2f(b2 - m);
    float lse = __builtin_amdgcn_logf(S) + m;

    float tl  = t0 * __builtin_amdgcn_logf(t0) + t1 * __builtin_amdgcn_logf(t1)
              + t2 * __builtin_amdgcn_logf(t2);
    float tb  = t0 * b0 + t1 * b1 + t2 * b2;
    float kl2 = tl - tb + lse;

    float c0 = l0 * LOG2E, c1 = l1 * LOG2E, c2 = l2 * LOG2E;
    float m2 = fmaxf(c0, fmaxf(c1, c2));
    float S2 = __builtin_amdgcn_exp2f(c0 - m2) + __builtin_amdgcn_exp2f(c1 - m2)
             + __builtin_amdgcn_exp2f(c2 - m2);
    float ll  = (lab == 0) ? c0 : ((lab == 1) ? c1 : c2);
    float ce2 = __builtin_amdgcn_logf(S2) + m2 - ll;

    return kl2 + ce2;
}

__global__ __launch_bounds__(BLOCK) void adl_main(
    const float4* __restrict__ l4,
    const int4*   __restrict__ h4,
    const float4* __restrict__ s4,
    const float4* __restrict__ c4,
    double*       __restrict__ partials,
    int B)
{
    // pad-13 layout: row = 12 floats (4 samples) stored with stride 13
    __shared__ float ldsL[(TILE / 4) * 13];   // 13312 B
    __shared__ float ldsS[(TILE / 4) * 13];   // 13312 B

    const int t      = threadIdx.x;
    const int nTiles = B / TILE;

    float part = 0.0f;
    float4 pL[3], pS[3], pC;
    int4   pH;

    int  tile = blockIdx.x;
    bool have = (tile < nTiles);
    if (have) {
#pragma unroll
        for (int k = 0; k < 3; ++k) {
            pL[k] = l4[tile * TF4 + k * BLOCK + t];
            pS[k] = s4[tile * TF4 + k * BLOCK + t];
        }
        pC = c4[tile * BLOCK + t];
        pH = h4[tile * BLOCK + t];
    }

    while (have) {
        __syncthreads();                       // LDS free (prev compute done)
        // registers -> LDS, transposed into pad-13 rows (≈2-way conflicts max)
#pragma unroll
        for (int k = 0; k < 3; ++k) {
            int f   = k * BLOCK + t;           // float4 index within tile
            int row = f / 3;                   // magic-mul div
            int r   = f - row * 3;
            float* dL = ldsL + 13 * row + 4 * r;
            float* dS = ldsS + 13 * row + 4 * r;
            float4 v = pL[k];
            dL[0] = v.x; dL[1] = v.y; dL[2] = v.z; dL[3] = v.w;
            float4 w = pS[k];
            dS[0] = w.x; dS[1] = w.y; dS[2] = w.z; dS[3] = w.w;
        }
        __syncthreads();

        float4 cC = pC;                        // keep current tile's conf/labels
        int4   cH = pH;

        int  nextTile = tile + GRID;
        bool haveNext = (nextTile < nTiles);
        if (haveNext) {                        // prefetch next tile (in flight
#pragma unroll                                 //  during this tile's compute)
            for (int k = 0; k < 3; ++k) {
                pL[k] = l4[nextTile * TF4 + k * BLOCK + t];
                pS[k] = s4[nextTile * TF4 + k * BLOCK + t];
            }
            pC = c4[nextTile * BLOCK + t];
            pH = h4[nextTile * BLOCK + t];
        }
        __builtin_amdgcn_sched_barrier(0);     // loads stay above compute

        const float* Lr = ldsL + 13 * t;       // lane stride 13 -> conflict-free
        const float* Sr = ldsS + 13 * t;
        float C[4] = {cC.x, cC.y, cC.z, cC.w};
        int   H[4] = {cH.x, cH.y, cH.z, cH.w};
#pragma unroll
        for (int i = 0; i < 4; ++i)
            part += sample2(Lr[3 * i], Lr[3 * i + 1], Lr[3 * i + 2],
                            Sr[3 * i], Sr[3 * i + 1], Sr[3 * i + 2],
                            C[i], H[i]);

        tile = nextTile;
        have = haveNext;
    }

    // generic tail (no-op when B % TILE == 0)
    {
        const float* lf = (const float*)l4;
        const float* sf = (const float*)s4;
        const float* cf = (const float*)c4;
        const int*   hf = (const int*)h4;
        for (int s = nTiles * TILE + blockIdx.x * BLOCK + t; s < B;
             s += GRID * BLOCK)
            part += sample2(lf[3 * s] * 1.0f, lf[3 * s + 1], lf[3 * s + 2],
                            sf[3 * s], sf[3 * s + 1], sf[3 * s + 2],
                            cf[s], hf[s]);
    }

    // wave reduce (fp32), block partial (f64), no atomics
#pragma unroll
    for (int off = 32; off > 0; off >>= 1)
        part += __shfl_down(part, off, 64);

    __shared__ double red[BLOCK / 64];
    int lane = t & 63, wid = t >> 6;
    if (lane == 0) red[wid] = (double)part;
    __syncthreads();
    if (t == 0)
        partials[blockIdx.x] = red[0] + red[1] + red[2] + red[3];
}

__global__ __launch_bounds__(256) void adl_finalize(
    const double* __restrict__ partials, float* __restrict__ out, double scale)
{
    int t = threadIdx.x;
    double s = 0.0;
    for (int i = t; i < GRID; i += 256) s += partials[i];
#pragma unroll
    for (int off = 32; off > 0; off >>= 1)
        s += __shfl_down(s, off, 64);
    __shared__ double red[4];
    if ((t & 63) == 0) red[t >> 6] = s;
    __syncthreads();
    if (t == 0) out[0] = (float)((red[0] + red[1] + red[2] + red[3]) * scale);
}

extern "C" void kernel_launch(void* const* d_in, const int* in_sizes, int n_in,
                              void* d_out, int out_size, void* d_ws, size_t ws_size,
                              hipStream_t stream) {
    const float* logits = (const float*)d_in[0];
    const int*   hard   = (const int*)d_in[1];
    const float* soft   = (const float*)d_in[2];
    const float* conf   = (const float*)d_in[3];

    int B = in_sizes[1];
    double* partials = (double*)d_ws;   // GRID doubles; every block writes its slot

    adl_main<<<GRID, BLOCK, 0, stream>>>((const float4*)logits, (const int4*)hard,
                                         (const float4*)soft, (const float4*)conf,
                                         partials, B);
    double scale = 0.5 * (double)LN2 / (double)B;
    adl_finalize<<<1, 256, 0, stream>>>(partials, (float*)d_out, scale);
}